// Round 2
// baseline (1126.845 us; speedup 1.0000x reference)
//
#include <hip/hip_runtime.h>

typedef _Float16 half8 __attribute__((ext_vector_type(8)));
typedef _Float16 half4 __attribute__((ext_vector_type(4)));
typedef float floatx4 __attribute__((ext_vector_type(4)));

// ---------------- workspace layout (bytes) ----------------
#define OFF_S    0L                      // 4 batches * 2048*2048 fp32 = 67108864
#define OFF_P    67108864L               // 4 batches * 2048*2048 fp16 = 33554432
#define OFF_MASK 100663296L              // 32768 u8
#define OFF_FLAGS 100696064L             // 512 u8 (16 batches * 32 chunks of 64 j)
#define OFF_W    134217728L              // 1024*1024 fp16 = 2097152
#define OFF_QK   136314880L              // 65536*1024 fp16 = 134217728 (Q rows 0.., K rows 32768..)
#define OFF_KT   270532608L              // 16*1024*2048 fp16 = 67108864
#define WS_NEED  337641472L

__device__ __forceinline__ void glds16(const void* g, void* l) {
  __builtin_amdgcn_global_load_lds(
      (__attribute__((address_space(1))) void*)(void*)(g),
      (__attribute__((address_space(3))) void*)(l), 16, 0, 0);
}

// ---------------- mask canonicalization + per-64j all-masked flags ----------------
__global__ void mask_canon(const unsigned* __restrict__ raw,
                           unsigned char* __restrict__ outm,
                           unsigned char* __restrict__ flags) {
  __shared__ int flag;
  int t = threadIdx.x;
  if (t == 0) flag = 0;
  __syncthreads();
  int loc = 0;
  for (int i = t; i < 8192; i += 256)      // 32KB scan: whole u8 array / first 1/4 of i32
    if (raw[i] > 1u) loc = 1;
  if (loc) flag = 1;                        // benign race
  __syncthreads();
  if (flag) {                               // u8 storage
    const unsigned char* b8 = (const unsigned char*)raw;
    for (int j = t; j < 32768; j += 256) outm[j] = (b8[j] != 0);
  } else {                                  // i32 storage
    const int* r32 = (const int*)raw;
    for (int j = t; j < 32768; j += 256) outm[j] = (r32[j] != 0);
  }
  __syncthreads();
  // 512 chunks of 64 consecutive j; flag=1 iff all masked
  for (int c = t; c < 512; c += 256) {
    const unsigned char* p = outm + c * 64;
    unsigned char all = 1;
    for (int k = 0; k < 64; k++) all &= p[k];
    flags[c] = all;
  }
}

// ---------------- fp32 -> fp16 convert (W only) ----------------
__global__ __launch_bounds__(256) void cvt_f32_f16(const float* __restrict__ x,
                                                   _Float16* __restrict__ y, long n) {
  long i = ((long)blockIdx.x * 256 + threadIdx.x) * 4;
  if (i + 3 < n) {
    float4 v = *(const float4*)(x + i);
    half4 h;
    h[0] = (_Float16)v.x; h[1] = (_Float16)v.y;
    h[2] = (_Float16)v.z; h[3] = (_Float16)v.w;
    *(half4*)(y + i) = h;
  }
}

// ---------------- projection GEMM: fp32 A staged+converted, fused bias+relu ----------------
// QK[m,n] = relu( sum_h X[m,h]*W[n,h] + b[n] ), M=65536 (inp rows then ctx rows), N=K=1024
__global__ __launch_bounds__(256, 3)
void gemm_proj(const float* __restrict__ Ainp, const float* __restrict__ Actx,
               const _Float16* __restrict__ Bw, _Float16* __restrict__ C,
               const float* __restrict__ bias) {
  __shared__ __align__(16) _Float16 As[128 * 64];
  __shared__ __align__(16) _Float16 Bs[128 * 64];
  const int t = threadIdx.x, l = t & 63, w = t >> 6;
  const float* A = (blockIdx.y < 256) ? Ainp : Actx;
  A += (long)(blockIdx.y & 255) * 128 * 1024;
  const _Float16* B = Bw + (long)blockIdx.x * 128 * 1024;
  const int waveM = (w >> 1) * 64, waveN = (w & 1) * 64;
  const int l15 = l & 15, quad = l >> 4;
  const int srow = l >> 3;                 // 0..7
  const int gcol = (l & 7) * 8;            // fp32 col offset within BK chunk group
  const int gchunkB = (l & 7) ^ (srow & 7);

  floatx4 acc[4][4] = {};

  for (int kt = 0; kt < 1024; kt += 64) {
    __syncthreads();
#pragma unroll
    for (int c = 0; c < 4; c++) {
      const int rb = w * 32 + c * 8;       // wave-uniform row base
      glds16(B + (long)(rb + srow) * 1024 + kt + gchunkB * 8, Bs + rb * 64);
      const int ra = rb + srow;
      float4 v0 = *(const float4*)(A + (long)ra * 1024 + kt + gcol);
      float4 v1 = *(const float4*)(A + (long)ra * 1024 + kt + gcol + 4);
      half8 h;
      h[0] = (_Float16)v0.x; h[1] = (_Float16)v0.y;
      h[2] = (_Float16)v0.z; h[3] = (_Float16)v0.w;
      h[4] = (_Float16)v1.x; h[5] = (_Float16)v1.y;
      h[6] = (_Float16)v1.z; h[7] = (_Float16)v1.w;
      const int ch = (l & 7) ^ (ra & 7);
      *(half8*)(As + ra * 64 + ch * 8) = h;
    }
    __syncthreads();
#pragma unroll
    for (int k32 = 0; k32 < 2; k32++) {
      half8 af[4], bfr[4];
#pragma unroll
      for (int mi = 0; mi < 4; mi++) {
        const int r = waveM + mi * 16 + l15;
        const int cc = (k32 * 4 + quad) ^ (r & 7);
        af[mi] = *(const half8*)(As + r * 64 + cc * 8);
      }
#pragma unroll
      for (int ni = 0; ni < 4; ni++) {
        const int r = waveN + ni * 16 + l15;
        const int cc = (k32 * 4 + quad) ^ (r & 7);
        bfr[ni] = *(const half8*)(Bs + r * 64 + cc * 8);
      }
#pragma unroll
      for (int mi = 0; mi < 4; mi++)
#pragma unroll
        for (int ni = 0; ni < 4; ni++)
          acc[mi][ni] = __builtin_amdgcn_mfma_f32_16x16x32_f16(af[mi], bfr[ni],
                                                               acc[mi][ni], 0, 0, 0);
    }
  }

  const int rowb = quad * 4;
  _Float16* Cp = C + (long)blockIdx.y * 128 * 1024 + blockIdx.x * 128;
#pragma unroll
  for (int mi = 0; mi < 4; mi++)
#pragma unroll
    for (int ni = 0; ni < 4; ni++) {
      const int col = waveN + ni * 16 + l15;
      const float bv = bias[blockIdx.x * 128 + col];
#pragma unroll
      for (int p = 0; p < 4; p++) {
        const int row = waveM + mi * 16 + rowb + p;
        Cp[(long)row * 1024 + col] = (_Float16)fmaxf(acc[mi][ni][p] + bv, 0.f);
      }
    }
}

// ---------------- NT GEMM, fp16 in / fp32 out, mask-aware ----------------
// MODE 1 (scores): skip whole block if both 64-j chunks of this x-tile are fully masked.
// MODE 2 (PV):     skip K-chunks (j) that are fully masked (P there is never written; it is 0).
template <int MODE>
__global__ __launch_bounds__(256, 3)
void gemm_nt(const _Float16* __restrict__ A, long sAz,
             const _Float16* __restrict__ B, long sBz,
             float* __restrict__ Cv, long sCz,
             const unsigned char* __restrict__ jflags, int K, int ldc) {
  if (MODE == 1) {
    const unsigned char* f = jflags + blockIdx.z * 32 + blockIdx.x * 2;
    if (f[0] & f[1]) return;
  }
  __shared__ __align__(16) _Float16 As[128 * 64];
  __shared__ __align__(16) _Float16 Bs[128 * 64];
  const int t = threadIdx.x;
  const int l = t & 63;
  const int w = t >> 6;
  A += (long)blockIdx.z * sAz + (long)blockIdx.y * 128 * K;
  B += (long)blockIdx.z * sBz + (long)blockIdx.x * 128 * K;
  const int waveM = (w >> 1) * 64, waveN = (w & 1) * 64;
  const int l15 = l & 15, quad = l >> 4;
  const int srow = l >> 3;
  const int gchunk = (l & 7) ^ (srow & 7);

  floatx4 acc[4][4] = {};

  for (int kt = 0; kt < K; kt += 64) {
    if (MODE == 2) {
      if (jflags[blockIdx.z * 32 + (kt >> 6)]) continue;   // block-uniform
    }
    __syncthreads();
#pragma unroll
    for (int c = 0; c < 4; c++) {
      const int r = w * 32 + c * 8;
      glds16(A + (long)(r + srow) * K + kt + gchunk * 8, As + r * 64);
      glds16(B + (long)(r + srow) * K + kt + gchunk * 8, Bs + r * 64);
    }
    __syncthreads();
#pragma unroll
    for (int k32 = 0; k32 < 2; k32++) {
      half8 af[4], bfr[4];
#pragma unroll
      for (int mi = 0; mi < 4; mi++) {
        const int r = waveM + mi * 16 + l15;
        const int cc = (k32 * 4 + quad) ^ (r & 7);
        af[mi] = *(const half8*)(As + r * 64 + cc * 8);
      }
#pragma unroll
      for (int ni = 0; ni < 4; ni++) {
        const int r = waveN + ni * 16 + l15;
        const int cc = (k32 * 4 + quad) ^ (r & 7);
        bfr[ni] = *(const half8*)(Bs + r * 64 + cc * 8);
      }
#pragma unroll
      for (int mi = 0; mi < 4; mi++)
#pragma unroll
        for (int ni = 0; ni < 4; ni++)
          acc[mi][ni] = __builtin_amdgcn_mfma_f32_16x16x32_f16(af[mi], bfr[ni],
                                                               acc[mi][ni], 0, 0, 0);
    }
  }

  const int rowb = quad * 4;
  float* Cp = Cv + (long)blockIdx.z * sCz +
              (long)blockIdx.y * 128 * ldc + blockIdx.x * 128;
#pragma unroll
  for (int mi = 0; mi < 4; mi++)
#pragma unroll
    for (int ni = 0; ni < 4; ni++) {
      const int col = waveN + ni * 16 + l15;
#pragma unroll
      for (int p = 0; p < 4; p++) {
        const int row = waveM + mi * 16 + rowb + p;
        Cp[(long)row * ldc + col] = acc[mi][ni][p];
      }
    }
}

// ---------------- K transpose (per batch, fp16) ----------------
__global__ __launch_bounds__(256) void transpose_k(const _Float16* __restrict__ Km,
                                                   _Float16* __restrict__ KT) {
  __shared__ _Float16 tile[64 * 72];
  const int t = threadIdx.x;
  const long b = blockIdx.z;
  const _Float16* src = Km + (b * 2048 + blockIdx.x * 64) * 1024 + blockIdx.y * 64;
  {
    const int jl = t >> 2, hc = (t & 3) * 16;
    half8 v0 = *(const half8*)(src + (long)jl * 1024 + hc);
    half8 v1 = *(const half8*)(src + (long)jl * 1024 + hc + 8);
    *(half8*)&tile[jl * 72 + hc] = v0;
    *(half8*)&tile[jl * 72 + hc + 8] = v1;
  }
  __syncthreads();
  {
    const int hl = t >> 2, jc = (t & 3) * 16;
    half8 o0, o1;
#pragma unroll
    for (int jj = 0; jj < 8; jj++) o0[jj] = tile[(jc + jj) * 72 + hl];
#pragma unroll
    for (int jj = 0; jj < 8; jj++) o1[jj] = tile[(jc + 8 + jj) * 72 + hl];
    long off = (b * 1024 + blockIdx.y * 64 + hl) * 2048 + blockIdx.x * 64 + jc;
    *(half8*)(KT + off) = o0;
    *(half8*)(KT + off + 8) = o1;
  }
}

// ---------------- masked softmax: S fp32 row -> P fp16 row, chunk-skipping ----------------
__global__ __launch_bounds__(256) void softmax_k(const float* __restrict__ S,
                                                 _Float16* __restrict__ P,
                                                 const unsigned char* __restrict__ mask,
                                                 const unsigned char* __restrict__ flags,
                                                 int b0) {
  const int i = blockIdx.x, z = blockIdx.y, t = threadIdx.x;
  const float* s = S + ((long)z * 2048 + i) * 2048;
  const unsigned char* mrow = mask + (long)(b0 + z) * 2048;
  const unsigned char* frow = flags + (long)(b0 + z) * 32;
  const int base0 = t * 4, base1 = 1024 + t * 4;
  const bool f0 = frow[base0 >> 6] != 0;
  const bool f1 = frow[base1 >> 6] != 0;
  const float NINF = -__builtin_inff();
  float v[8] = {NINF, NINF, NINF, NINF, NINF, NINF, NINF, NINF};
  if (!f0) {
    float4 a0 = *(const float4*)(s + base0);
    v[0] = a0.x; v[1] = a0.y; v[2] = a0.z; v[3] = a0.w;
#pragma unroll
    for (int k = 0; k < 4; k++)
      if (mrow[base0 + k]) v[k] = NINF;
  }
  if (!f1) {
    float4 a1 = *(const float4*)(s + base1);
    v[4] = a1.x; v[5] = a1.y; v[6] = a1.z; v[7] = a1.w;
#pragma unroll
    for (int k = 0; k < 4; k++)
      if (mrow[base1 + k]) v[4 + k] = NINF;
  }
  float mx = v[0];
#pragma unroll
  for (int k = 1; k < 8; k++) mx = fmaxf(mx, v[k]);
#pragma unroll
  for (int o = 32; o >= 1; o >>= 1) mx = fmaxf(mx, __shfl_xor(mx, o, 64));
  __shared__ float redm[4], reds[4];
  if ((t & 63) == 0) redm[t >> 6] = mx;
  __syncthreads();
  mx = fmaxf(fmaxf(redm[0], redm[1]), fmaxf(redm[2], redm[3]));
  float e[8], sm = 0.f;
#pragma unroll
  for (int k = 0; k < 8; k++) { e[k] = __expf(v[k] - mx); sm += e[k]; }
#pragma unroll
  for (int o = 32; o >= 1; o >>= 1) sm += __shfl_xor(sm, o, 64);
  if ((t & 63) == 0) reds[t >> 6] = sm;
  __syncthreads();
  sm = reds[0] + reds[1] + reds[2] + reds[3];
  const float inv = 1.0f / sm;   // never a fully-masked row
  _Float16* p = P + ((long)z * 2048 + i) * 2048;
  if (!f0) {
    half4 h0;
#pragma unroll
    for (int k = 0; k < 4; k++) h0[k] = (_Float16)(e[k] * inv);
    *(half4*)(p + base0) = h0;
  }
  if (!f1) {
    half4 h1;
#pragma unroll
    for (int k = 0; k < 4; k++) h1[k] = (_Float16)(e[4 + k] * inv);
    *(half4*)(p + base1) = h1;
  }
}

extern "C" void kernel_launch(void* const* d_in, const int* in_sizes, int n_in,
                              void* d_out, int out_size, void* d_ws, size_t ws_size,
                              hipStream_t stream) {
  (void)in_sizes; (void)n_in; (void)out_size;
  if ((long)ws_size < WS_NEED) return;  // workspace too small: leave out poisoned as a clear signal

  const float* inp  = (const float*)d_in[0];
  const float* ctx  = (const float*)d_in[1];
  const unsigned* msk = (const unsigned*)d_in[2];
  const float* W    = (const float*)d_in[3];
  const float* bias = (const float*)d_in[4];
  float* out = (float*)d_out;
  char* ws = (char*)d_ws;

  float*    Sb   = (float*)(ws + OFF_S);
  _Float16* Pb   = (_Float16*)(ws + OFF_P);
  _Float16* Wf   = (_Float16*)(ws + OFF_W);
  _Float16* QK   = (_Float16*)(ws + OFF_QK);
  _Float16* KT   = (_Float16*)(ws + OFF_KT);
  unsigned char* Mc = (unsigned char*)(ws + OFF_MASK);
  unsigned char* Fl = (unsigned char*)(ws + OFF_FLAGS);

  // 1. canonical mask + all-masked chunk flags
  mask_canon<<<1, 256, 0, stream>>>(msk, Mc, Fl);
  // 2. W fp32 -> fp16 (X conversion is fused into gemm_proj)
  cvt_f32_f16<<<1024, 256, 0, stream>>>(W, Wf, 1048576L);
  // 3. projection: QK = relu([inp;ctx] @ W^T + b), M=65536, N=1024, K=1024
  gemm_proj<<<dim3(8, 512, 1), 256, 0, stream>>>(inp, ctx, Wf, QK, bias);
  // 4. K^T per batch
  transpose_k<<<dim3(32, 16, 16), 256, 0, stream>>>(QK + 32768L * 1024, KT);
  // 5. per 4-batch quad: scores -> softmax -> PV, all mask-aware
  for (int bp = 0; bp < 4; bp++) {
    const _Float16* Aq = QK + (long)bp * 4 * 2048 * 1024;
    const _Float16* Bk = QK + (32768L + (long)bp * 4 * 2048) * 1024;
    const unsigned char* Fq = Fl + bp * 4 * 32;
    gemm_nt<1><<<dim3(16, 16, 4), 256, 0, stream>>>(Aq, 2048L * 1024, Bk, 2048L * 1024,
                                                    Sb, 2048L * 2048, Fq, 1024, 2048);
    softmax_k<<<dim3(2048, 4), 256, 0, stream>>>(Sb, Pb, Mc, Fl, bp * 4);
    gemm_nt<2><<<dim3(8, 16, 4), 256, 0, stream>>>(Pb, 2048L * 2048,
                                                   KT + (long)bp * 4 * 1024 * 2048,
                                                   1024L * 2048,
                                                   out + (long)bp * 4 * 2048 * 1024,
                                                   2048L * 1024, Fq, 2048, 1024);
  }
}